// Round 10
// baseline (98.328 us; speedup 1.0000x reference)
//
#include <hip/hip_runtime.h>

// GruDirection3d forward, d1=d2=d3=1. B=2, C=96, D=H=W=32.
// out[b,c,d,y,x] = z*h_tilde + (1-z)*out[b,c,d-1,y-1,x-1], border = h0.
//
// POSITION-SPACE HELIX, float4 / 16B-per-lane (round-10).
//
// Thread (a,bg) owns the aligned float4 at x=4bg..4bg+3 of row
// y=(a+d)&31 at plane d (y rotates, x fixed -> vector never wraps).
// In position space the recurrence is
//     h_d[y][x] = z*ht + (1-z) * h_{d-1}[y-1][x-1]
// and this thread's previous-plane registers ARE row y-1 (the rotation
// walks y by +1 per plane), so the predecessor vector is just
// (neighbor's h.w via one __shfl_up, own h.x, h.y, h.z).
// Borders: y-wrap ((a+d)&31==0) resets the whole row's pred to h0;
// x==0 (bg==0, component 0) resets to h0; d==0 is covered by h=h0 init.
//
// WHY: r2-r9 exonerated sync, pattern, ring depth, scheduling, and TLP
// (the harness fills do 6.4 TB/s at 2.6 waves/CU). The single property
// shared by every >=6 TB/s kernel on this chip (fills, m13 copy) and by
// no gru variant so far: 16 B/lane LANE-CONTIGUOUS accesses. Here lane
// = r*8+bg makes a wave's 8 rows memory-consecutive -> every load/store
// instruction moves one contiguous 1 KB block. No LDS, no barriers.
// Depth-8 float4 ring pinned with sched_barrier(0): 16 outstanding 1KB
// loads/wave, ~48 KB/CU in flight at 3 blocks/CU on all 256 CUs.

#define DD 32
#define PF 8                    // ring depth (planes): 16 loads in flight

__global__ __launch_bounds__(64) void gru3d_row4(
    const float* __restrict__ z,
    const float* __restrict__ ht,
    const float* __restrict__ h0p,
    float* __restrict__ out)
{
    const int blk  = blockIdx.x;        // 0..767 = slab*4 + band
    const int slab = blk >> 2;          // 0..191  (b*96 + c)
    const int band = blk & 3;           // 8-row band of 'a'
    const int lane = threadIdx.x;       // 0..63 = r*8 + bg  (rows slower!)
    const int r    = lane >> 3;
    const int bg   = lane & 7;          // x-group: x = 4bg..4bg+3
    const int a    = (band << 3) | r;

    const float h0 = h0p[0];

    const size_t base = (size_t)slab * (DD * 1024);
    const float* __restrict__ zb = z   + base;
    const float* __restrict__ tb = ht  + base;
    float*       __restrict__ ob = out + base;

    // Float offset of this thread's float4 at plane d (16B-aligned).
    // Wave covers rows a..a+7 (consecutive mod 32) -> contiguous 1KB/instr.
    auto off = [&](int d) -> int {
        return (d << 10) | (((a + d) & 31) << 5) | (bg << 2);
    };

    // Prologue: fill the ring (16 x 1KB loads in flight), then fence so
    // the scheduler cannot sink them to their uses.
    float4 zr[PF], tr[PF];
    #pragma unroll
    for (int p = 0; p < PF; ++p) {
        zr[p] = *reinterpret_cast<const float4*>(zb + off(p));
        tr[p] = *reinterpret_cast<const float4*>(tb + off(p));
    }
    __builtin_amdgcn_sched_barrier(0);

    float4 h = make_float4(h0, h0, h0, h0);   // "plane -1" row = border

    #pragma unroll
    for (int d = 0; d < DD; ++d) {
        const int s = d % PF;               // compile-time under full unroll

        // Predecessor vector = previous row shifted +1 in x.
        const float up = __shfl_up(h.w, 1); // lane bg-1's x=4bg-1 value
        float p0 = (bg == 0) ? h0 : up;     // x==0 face -> border
        float p1 = h.x, p2 = h.y, p3 = h.z;
        if (((a + d) & 31) == 0) {          // y==0 face -> whole row border
            p0 = h0; p1 = h0; p2 = h0; p3 = h0;
        }

        const float4 zv = zr[s], tv = tr[s];
        h.x = fmaf(zv.x, tv.x - p0, p0);    // z*ht + (1-z)*pred
        h.y = fmaf(zv.y, tv.y - p1, p1);
        h.z = fmaf(zv.z, tv.z - p2, p2);
        h.w = fmaf(zv.w, tv.w - p3, p3);

        *reinterpret_cast<float4*>(ob + off(d)) = h;   // contiguous 1KB store

        if (d + PF < DD) {                  // refill ring, PF planes ahead
            zr[s] = *reinterpret_cast<const float4*>(zb + off(d + PF));
            tr[s] = *reinterpret_cast<const float4*>(tb + off(d + PF));
        }
        __builtin_amdgcn_sched_barrier(0);  // pin: refills stay PF ahead
    }
}

extern "C" void kernel_launch(void* const* d_in, const int* in_sizes, int n_in,
                              void* d_out, int out_size, void* d_ws, size_t ws_size,
                              hipStream_t stream) {
    const float* z  = (const float*)d_in[0];
    const float* ht = (const float*)d_in[1];
    const float* h0 = (const float*)d_in[2];
    float* out      = (float*)d_out;

    const int BC = 2 * 96;               // 192 slabs, 4 bands each
    gru3d_row4<<<dim3(BC * 4), dim3(64), 0, stream>>>(z, ht, h0, out);
}